// Round 14
// baseline (83.356 us; speedup 1.0000x reference)
//
#include <hip/hip_runtime.h>
#include <hip/hip_bf16.h>
#include <math.h>

#define B_   2
#define N_   8192
#define D_   256
#define C_   6
#define HF_  64
#define WF_  64
#define P_   4
#define BN_  (B_ * N_)   // 16384

typedef __attribute__((ext_vector_type(8))) short short8v;   // 8 bf16 (4 VGPRs)
typedef __attribute__((ext_vector_type(4))) float floatx4;

typedef unsigned short ushort_t;
typedef __attribute__((ext_vector_type(4))) unsigned short ushort4_t;
typedef __attribute__((ext_vector_type(8))) unsigned short ushort8_t;

__device__ __forceinline__ float wred64(float v) {
#pragma unroll
  for (int o = 32; o > 0; o >>= 1) v += __shfl_xor(v, o, 64);
  return v;
}

__device__ __forceinline__ ushort_t f2b(float x) {
  union { float f; unsigned u; } c;
  c.f = x;
  unsigned r = c.u + 0x7FFFu + ((c.u >> 16) & 1u);
  return (ushort_t)(r >> 16);
}

__device__ __forceinline__ float b2f(ushort_t u) {
  union { unsigned u; float f; } c;
  c.u = ((unsigned)u) << 16;
  return c.f;
}

// ---------------------------------------------------------------------------
// K_rest:
//  blocks [0,32)   : weight products via MFMA, 64x64 tiles
//  blocks [32,36)  : vec1/vec2/beta, 64 outputs each, 4-way wave-parallel
//  block 36        : wg05/wbb05 (offset constants) + bqbk
//  blocks [37,+2048): LayerNorm, 2 rows per wave (32-lane halves, 8 ch/lane)
// ---------------------------------------------------------------------------
__global__ __launch_bounds__(256) void k_rest(
    const float* __restrict__ Wq, const float* __restrict__ Wk,
    const float* __restrict__ Wv, const float* __restrict__ Wo,
    const float* __restrict__ bq, const float* __restrict__ bk,
    const float* __restrict__ bv,
    ushort_t* __restrict__ At, ushort_t* __restrict__ W2t,
    float* __restrict__ vec1, float* __restrict__ vec2,
    float* __restrict__ beta, float* __restrict__ bqbk,
    const float* __restrict__ Q, const float* __restrict__ ln_g,
    const float* __restrict__ ln_b, const float* __restrict__ Woff,
    const float* __restrict__ boff, ushort_t* __restrict__ QNb,
    float* __restrict__ LNA, float* __restrict__ RSMU,
    float* __restrict__ WG05, float* __restrict__ WBB05) {
  __shared__ ushort_t Ak[64 * 68];   // 8.7 KB (reused as float scratch by vec)
  __shared__ ushort_t Bk[64 * 68];   // 8.7 KB
  const int blk = blockIdx.x;
  const int t = threadIdx.x;

  if (blk < 32) {
    const int prod = blk >> 4;
    const int tb = blk & 15;
    const int rb = (tb >> 2) * 64;   // output row base (j or d)
    const int cb = (tb & 3) * 64;    // output col base (i or e)
    const int wid = t >> 6, lane = t & 63;
    const int wm = wid >> 1, wn = wid & 1;
    const int lr = lane & 15, lh = lane >> 4;
    floatx4 acc[2][2];
#pragma unroll
    for (int i = 0; i < 2; ++i)
#pragma unroll
      for (int j = 0; j < 2; ++j) acc[i][j] = (floatx4){0.f, 0.f, 0.f, 0.f};

    for (int m0 = 0; m0 < 256; m0 += 64) {
      if (prod == 0) {
#pragma unroll
        for (int seg = 0; seg < 4; ++seg) {
          const int mm = (t >> 4) + seg * 16;  // 0..63
          const int cc = (t & 15) * 4;         // 0..60
          const float4 va = *(const float4*)&Wk[(m0 + mm) * 256 + rb + cc];
          Ak[(cc + 0) * 68 + mm] = f2b(va.x);
          Ak[(cc + 1) * 68 + mm] = f2b(va.y);
          Ak[(cc + 2) * 68 + mm] = f2b(va.z);
          Ak[(cc + 3) * 68 + mm] = f2b(va.w);
          const float4 vb = *(const float4*)&Wq[(m0 + mm) * 256 + cb + cc];
          Bk[(cc + 0) * 68 + mm] = f2b(vb.x);
          Bk[(cc + 1) * 68 + mm] = f2b(vb.y);
          Bk[(cc + 2) * 68 + mm] = f2b(vb.z);
          Bk[(cc + 3) * 68 + mm] = f2b(vb.w);
        }
      } else {
#pragma unroll
        for (int seg = 0; seg < 4; ++seg) {
          const int row = (t >> 4) + seg * 16;  // 0..63
          const int c4 = (t & 15) * 4;          // 0..60
          const float4 va = *(const float4*)&Wo[(rb + row) * 256 + m0 + c4];
          Ak[row * 68 + c4 + 0] = f2b(va.x);
          Ak[row * 68 + c4 + 1] = f2b(va.y);
          Ak[row * 68 + c4 + 2] = f2b(va.z);
          Ak[row * 68 + c4 + 3] = f2b(va.w);
          const float4 vb = *(const float4*)&Wv[(m0 + row) * 256 + cb + c4];
          Bk[(c4 + 0) * 68 + row] = f2b(vb.x);
          Bk[(c4 + 1) * 68 + row] = f2b(vb.y);
          Bk[(c4 + 2) * 68 + row] = f2b(vb.z);
          Bk[(c4 + 3) * 68 + row] = f2b(vb.w);
        }
      }
      __syncthreads();
#pragma unroll
      for (int kk = 0; kk < 64; kk += 32) {
        short8v a[2], b[2];
#pragma unroll
        for (int mi = 0; mi < 2; ++mi)
          a[mi] = *(const short8v*)&Ak[(wm * 32 + mi * 16 + lr) * 68 + kk + lh * 8];
#pragma unroll
        for (int ni = 0; ni < 2; ++ni)
          b[ni] = *(const short8v*)&Bk[(wn * 32 + ni * 16 + lr) * 68 + kk + lh * 8];
#pragma unroll
        for (int mi = 0; mi < 2; ++mi)
#pragma unroll
          for (int ni = 0; ni < 2; ++ni)
            acc[mi][ni] = __builtin_amdgcn_mfma_f32_16x16x32_bf16(
                a[mi], b[ni], acc[mi][ni], 0, 0, 0);
      }
      __syncthreads();
    }
    ushort_t* dst = prod ? W2t : At;
#pragma unroll
    for (int mi = 0; mi < 2; ++mi)
#pragma unroll
      for (int ni = 0; ni < 2; ++ni)
#pragma unroll
        for (int r = 0; r < 4; ++r)
          dst[(size_t)(rb + wm * 32 + mi * 16 + lh * 4 + r) * 256 +
              cb + wn * 32 + ni * 16 + lr] = f2b(acc[mi][ni][r]);
    return;
  }

  if (blk < 36) {
    // vec1/vec2/beta: 64 outputs per block, 4 waves split the m-range.
    const int vb = blk - 32;
    const int i = t & 63, seg = t >> 6;
    const int ii = vb * 64 + i;
    float a2 = 0.f, a1 = 0.f, ab = 0.f;
#pragma unroll 4
    for (int mq = 0; mq < 64; ++mq) {
      const int m = seg * 64 + mq;
      a2 += Wq[m * 256 + ii] * bk[m];
      a1 += Wk[m * 256 + ii] * bq[m];
      ab += Wo[ii * 256 + m] * bv[m];
    }
    float* sc = (float*)Ak;  // 768 floats scratch
    sc[seg * 64 + i] = a2;
    sc[256 + seg * 64 + i] = a1;
    sc[512 + seg * 64 + i] = ab;
    __syncthreads();
    if (t < 64) {
      vec2[vb * 64 + t] = sc[t] + sc[64 + t] + sc[128 + t] + sc[192 + t];
      vec1[vb * 64 + t] =
          sc[256 + t] + sc[320 + t] + sc[384 + t] + sc[448 + t];
      beta[vb * 64 + t] =
          sc[512 + t] + sc[576 + t] + sc[640 + t] + sc[704 + t];
    }
    return;
  }

  if (blk == 36) {
    // offset constants + bqbk
    if (t < 8) {
      float wg = 0.f;
#pragma unroll 8
      for (int d = 0; d < 256; ++d) wg += Woff[t * 256 + d] * ln_g[d];
      WG05[t] = 0.05f * wg;
    } else if (t < 16) {
      const int p = t - 8;
      float wb = 0.f;
#pragma unroll 8
      for (int d = 0; d < 256; ++d) wb += Woff[p * 256 + d] * ln_b[d];
      WBB05[p] = 0.05f * (wb + boff[p]);
    } else if (t >= 64 && t < 128) {
      const int l = t - 64;
      float s = 0.f;
#pragma unroll
      for (int q = 0; q < 4; ++q) {
        const int m = l + q * 64;
        s += bq[m] * bk[m];
      }
      s = wred64(s);
      if (l == 0) *bqbk = s;
    }
    return;
  }

  // ---- LayerNorm: 2 rows per wave (32-lane halves, 8 channels/lane).
  const int lb = blk - 37;
  const int wave = t >> 6, lane = t & 63;
  const int half = lane >> 5, l = lane & 31;
  const int m = lb * 8 + wave * 2 + half;
  const int base = m * 256 + l * 8;
  const float4 x0 = *(const float4*)&Q[base];
  const float4 x1 = *(const float4*)&Q[base + 4];
  const float4 g0 = *(const float4*)&ln_g[l * 8];
  const float4 g1 = *(const float4*)&ln_g[l * 8 + 4];
  const float4 b0 = *(const float4*)&ln_b[l * 8];
  const float4 b1 = *(const float4*)&ln_b[l * 8 + 4];
  float xv[8] = {x0.x, x0.y, x0.z, x0.w, x1.x, x1.y, x1.z, x1.w};
  float gv[8] = {g0.x, g0.y, g0.z, g0.w, g1.x, g1.y, g1.z, g1.w};
  float bv8[8] = {b0.x, b0.y, b0.z, b0.w, b1.x, b1.y, b1.z, b1.w};
  float red[10];
  red[0] = 0.f;
  red[1] = 0.f;
#pragma unroll
  for (int j = 0; j < 8; ++j) {
    red[0] += xv[j];
    red[1] += xv[j] * xv[j];
  }
#pragma unroll
  for (int p = 0; p < 8; ++p) {
    const float4 w0 = *(const float4*)&Woff[p * 256 + l * 8];
    const float4 w1 = *(const float4*)&Woff[p * 256 + l * 8 + 4];
    red[2 + p] = w0.x * gv[0] * xv[0] + w0.y * gv[1] * xv[1] +
                 w0.z * gv[2] * xv[2] + w0.w * gv[3] * xv[3] +
                 w1.x * gv[4] * xv[4] + w1.y * gv[5] * xv[5] +
                 w1.z * gv[6] * xv[6] + w1.w * gv[7] * xv[7];
  }
#pragma unroll
  for (int o = 16; o > 0; o >>= 1) {
#pragma unroll
    for (int i = 0; i < 10; ++i) red[i] += __shfl_xor(red[i], o, 64);
  }
  const float mu = red[0] * (1.0f / 256.0f);
  const float var = red[1] * (1.0f / 256.0f) - mu * mu;
  const float rs = rsqrtf(var + 1e-5f);
  ushort8_t qo;
#pragma unroll
  for (int j = 0; j < 8; ++j)
    qo[j] = f2b((xv[j] - mu) * rs * gv[j] + bv8[j]);
  *(ushort8_t*)&QNb[base] = qo;
  if (l == 0) {
    const float s05 = 0.05f * rs;
    float4 o0, o1;
    o0.x = s05 * red[2]; o0.y = s05 * red[3];
    o0.z = s05 * red[4]; o0.w = s05 * red[5];
    o1.x = s05 * red[6]; o1.y = s05 * red[7];
    o1.z = s05 * red[8]; o1.w = s05 * red[9];
    *(float4*)&LNA[m * 8] = o0;
    *(float4*)&LNA[m * 8 + 4] = o1;
    RSMU[m] = rs * mu;
  }
}

// ---------------------------------------------------------------------------
// K_mid: merged feature cvt + GEMM0. cvt blocks FIRST (streaming starts at
// dispatch 0), gemm blocks fill in behind (L2-resident compute).
// ---------------------------------------------------------------------------
__global__ __launch_bounds__(256) void k_mid(
    const ushort_t* __restrict__ Xb, const ushort_t* __restrict__ Wt,
    ushort_t* __restrict__ Yout, const float* __restrict__ vec1,
    const float* __restrict__ f, ushort_t* __restrict__ fb, int totalVec4,
    int cvtBlocks) {
  __shared__ ushort_t As[64 * 68];
  __shared__ ushort_t Bs[64 * 68];
  __shared__ float tr[4][16 * 17];
  const int t = threadIdx.x;

  if (blockIdx.x < cvtBlocks) {
    const int stride = cvtBlocks * 256;
    for (int i = blockIdx.x * 256 + t; i < totalVec4; i += stride) {
      const float4 v = *(const float4*)&f[(size_t)i * 4];
      ushort4_t o;
      o.x = f2b(v.x); o.y = f2b(v.y); o.z = f2b(v.z); o.w = f2b(v.w);
      *(ushort4_t*)&fb[(size_t)i * 4] = o;
    }
    return;
  }

  const int gb = blockIdx.x - cvtBlocks;
  const int nb = gb & 3, mb = gb >> 2;
  const int m0 = mb * 64, n0 = nb * 64;
  const int wid = t >> 6, lane = t & 63;
  const int wm = wid >> 1, wn = wid & 1;
  const int lr = lane & 15, lh = lane >> 4;

  floatx4 acc[2][2];
#pragma unroll
  for (int i = 0; i < 2; ++i)
#pragma unroll
    for (int j = 0; j < 2; ++j) acc[i][j] = (floatx4){0.f, 0.f, 0.f, 0.f};

  for (int k0 = 0; k0 < 256; k0 += 64) {
#pragma unroll
    for (int q = 0; q < 2; ++q) {
      const int s = t * 2 + q;
      const int row = s >> 3;
      const int off = (s & 7) * 8;
      *(float4*)&As[row * 68 + off] =
          *(const float4*)(Xb + (size_t)(m0 + row) * 256 + k0 + off);
      *(float4*)&Bs[row * 68 + off] =
          *(const float4*)(Wt + (size_t)(n0 + row) * 256 + k0 + off);
    }
    __syncthreads();
#pragma unroll
    for (int kk = 0; kk < 64; kk += 32) {
      short8v a[2], b[2];
#pragma unroll
      for (int mi = 0; mi < 2; ++mi)
        a[mi] = *(const short8v*)&As[(wm * 32 + mi * 16 + lr) * 68 + kk + lh * 8];
#pragma unroll
      for (int ni = 0; ni < 2; ++ni)
        b[ni] = *(const short8v*)&Bs[(wn * 32 + ni * 16 + lr) * 68 + kk + lh * 8];
#pragma unroll
      for (int mi = 0; mi < 2; ++mi)
#pragma unroll
        for (int ni = 0; ni < 2; ++ni)
          acc[mi][ni] = __builtin_amdgcn_mfma_f32_16x16x32_bf16(
              a[mi], b[ni], acc[mi][ni], 0, 0, 0);
    }
    __syncthreads();
  }

  float* tb = tr[wid];
#pragma unroll
  for (int mi = 0; mi < 2; ++mi) {
#pragma unroll
    for (int ni = 0; ni < 2; ++ni) {
#pragma unroll
      for (int r = 0; r < 4; ++r)
        tb[(lh * 4 + r) * 17 + lr] = acc[mi][ni][r];
      const float4 v = *(const float4*)&tb[lr * 17 + lh * 4];
      const int row = m0 + wm * 32 + mi * 16 + lr;
      const int col = n0 + wn * 32 + ni * 16 + lh * 4;
      const float4 vc = *(const float4*)&vec1[col];
      ushort4_t o;
      o.x = f2b(v.x + vc.x);
      o.y = f2b(v.y + vc.y);
      o.z = f2b(v.z + vc.z);
      o.w = f2b(v.w + vc.w);
      *(ushort4_t*)(Yout + (size_t)row * 256 + col) = o;
    }
  }
}

// ---------------------------------------------------------------------------
// Final GEMM: out = SVb @ W2t^T + resid + wsc*beta + bo (f32 out).
// ---------------------------------------------------------------------------
__global__ __launch_bounds__(256) void k_gemm1(
    const ushort_t* __restrict__ Xb, const ushort_t* __restrict__ Wt,
    float* __restrict__ Yout, const float* __restrict__ resid,
    const float* __restrict__ wsc, const float* __restrict__ beta,
    const float* __restrict__ bo) {
  __shared__ ushort_t As[64 * 68];
  __shared__ ushort_t Bs[64 * 68];
  __shared__ float tr[4][16 * 17];
  const int t = threadIdx.x;
  const int nb = blockIdx.x & 3, mb = blockIdx.x >> 2;
  const int m0 = mb * 64, n0 = nb * 64;
  const int wid = t >> 6, lane = t & 63;
  const int wm = wid >> 1, wn = wid & 1;
  const int lr = lane & 15, lh = lane >> 4;

  floatx4 acc[2][2];
#pragma unroll
  for (int i = 0; i < 2; ++i)
#pragma unroll
    for (int j = 0; j < 2; ++j) acc[i][j] = (floatx4){0.f, 0.f, 0.f, 0.f};

  for (int k0 = 0; k0 < 256; k0 += 64) {
#pragma unroll
    for (int q = 0; q < 2; ++q) {
      const int s = t * 2 + q;
      const int row = s >> 3;
      const int off = (s & 7) * 8;
      *(float4*)&As[row * 68 + off] =
          *(const float4*)(Xb + (size_t)(m0 + row) * 256 + k0 + off);
      *(float4*)&Bs[row * 68 + off] =
          *(const float4*)(Wt + (size_t)(n0 + row) * 256 + k0 + off);
    }
    __syncthreads();
#pragma unroll
    for (int kk = 0; kk < 64; kk += 32) {
      short8v a[2], b[2];
#pragma unroll
      for (int mi = 0; mi < 2; ++mi)
        a[mi] = *(const short8v*)&As[(wm * 32 + mi * 16 + lr) * 68 + kk + lh * 8];
#pragma unroll
      for (int ni = 0; ni < 2; ++ni)
        b[ni] = *(const short8v*)&Bs[(wn * 32 + ni * 16 + lr) * 68 + kk + lh * 8];
#pragma unroll
      for (int mi = 0; mi < 2; ++mi)
#pragma unroll
        for (int ni = 0; ni < 2; ++ni)
          acc[mi][ni] = __builtin_amdgcn_mfma_f32_16x16x32_bf16(
              a[mi], b[ni], acc[mi][ni], 0, 0, 0);
    }
    __syncthreads();
  }

  float* tb = tr[wid];
#pragma unroll
  for (int mi = 0; mi < 2; ++mi) {
#pragma unroll
    for (int ni = 0; ni < 2; ++ni) {
#pragma unroll
      for (int r = 0; r < 4; ++r)
        tb[(lh * 4 + r) * 17 + lr] = acc[mi][ni][r];
      const float4 v = *(const float4*)&tb[lr * 17 + lh * 4];
      const int row = m0 + wm * 32 + mi * 16 + lr;
      const int col = n0 + wn * 32 + ni * 16 + lh * 4;
      const float4 rv = *(const float4*)&resid[(size_t)row * 256 + col];
      const float4 bt = *(const float4*)&beta[col];
      const float4 bv4 = *(const float4*)&bo[col];
      const float wscale = wsc[row];
      float4 o;
      o.x = v.x + rv.x + wscale * bt.x + bv4.x;
      o.y = v.y + rv.y + wscale * bt.y + bv4.y;
      o.z = v.z + rv.z + wscale * bt.z + bv4.z;
      o.w = v.w + rv.w + wscale * bt.w + bv4.w;
      *(float4*)&Yout[(size_t)row * 256 + col] = o;
    }
  }
}

// ---------------------------------------------------------------------------
// Fused sampling + scores + aggregation (bf16 features only).
// 512-thread blocks, 2 queries per wave (32-lane halves, 8 ch/lane, 16B
// gathers), 5-stage interleaved butterflies.
// ---------------------------------------------------------------------------
__global__ __launch_bounds__(512) void k_sample(
    const ushort_t* __restrict__ feats, const float* __restrict__ pix,
    const int* __restrict__ vmask, const ushort_t* __restrict__ Tb,
    const ushort_t* __restrict__ QNb, const float* __restrict__ vec2,
    const float* __restrict__ bqbk, const float* __restrict__ LNA,
    const float* __restrict__ RSMU, const float* __restrict__ WG05,
    const float* __restrict__ WBB05, ushort_t* __restrict__ SVb,
    float* __restrict__ wscale) {
  const int wave = threadIdx.x >> 6, lane = threadIdx.x & 63;
  const int half = lane >> 5, l = lane & 31;
  const int m = blockIdx.x * 16 + wave * 2 + half;
  const int b = m >> 13, n = m & 8191;

  const ushort8_t tu = *(const ushort8_t*)&Tb[(size_t)m * 256 + l * 8];
  float tf[8];
#pragma unroll
  for (int j = 0; j < 8; ++j) tf[j] = b2f(tu[j]);

  float dpg0;
  {
    const ushort8_t qu = *(const ushort8_t*)&QNb[(size_t)m * 256 + l * 8];
    const float4 v20 = *(const float4*)&vec2[l * 8];
    const float4 v21 = *(const float4*)&vec2[l * 8 + 4];
    dpg0 = v20.x * b2f(qu[0]) + v20.y * b2f(qu[1]) + v20.z * b2f(qu[2]) +
           v20.w * b2f(qu[3]) + v21.x * b2f(qu[4]) + v21.y * b2f(qu[5]) +
           v21.z * b2f(qu[6]) + v21.w * b2f(qu[7]);
  }

  float offv[8];
  {
    const float4 a0 = *(const float4*)&LNA[m * 8];
    const float4 a1 = *(const float4*)&LNA[m * 8 + 4];
    const float rsmu = RSMU[m];
    const float4 wg0 = *(const float4*)&WG05[0];
    const float4 wg1 = *(const float4*)&WG05[4];
    const float4 wb0 = *(const float4*)&WBB05[0];
    const float4 wb1 = *(const float4*)&WBB05[4];
    offv[0] = a0.x - rsmu * wg0.x + wb0.x;
    offv[1] = a0.y - rsmu * wg0.y + wb0.y;
    offv[2] = a0.z - rsmu * wg0.z + wb0.z;
    offv[3] = a0.w - rsmu * wg0.w + wb0.w;
    offv[4] = a1.x - rsmu * wg1.x + wb1.x;
    offv[5] = a1.y - rsmu * wg1.y + wb1.y;
    offv[6] = a1.z - rsmu * wg1.z + wb1.z;
    offv[7] = a1.w - rsmu * wg1.w + wb1.w;
  }
  const bool same = (offv[0] == offv[2]) && (offv[0] == offv[4]) &&
                    (offv[0] == offv[6]) && (offv[1] == offv[3]) &&
                    (offv[1] == offv[5]) && (offv[1] == offv[7]);

  int validc[6];
  float pcx[6], pcy[6];
#pragma unroll
  for (int c = 0; c < 6; ++c) {
    const int idx = (b * 6 + c) * 8192 + n;
    validc[c] = vmask[idx];
    pcx[c] = pix[(size_t)idx * 2 + 0];
    pcy[c] = pix[(size_t)idx * 2 + 1];
  }

  float smc[6][8];
#pragma unroll
  for (int c = 0; c < 6; ++c)
#pragma unroll
    for (int j = 0; j < 8; ++j) smc[c][j] = 0.f;

#pragma unroll
  for (int c = 0; c < 6; ++c) {
    if (!validc[c]) continue;
    const ushort_t* fb = feats + (size_t)(b * 6 + c) * (HF_ * WF_ * 256);
    auto samplePoint = [&](float gx, float gy, float scale) {
      const float fx = (gx + 1.f) * 31.5f;
      const float fy = (gy + 1.f) * 31.5f;
      const float x0f = floorf(fx), y0f = floorf(fy);
      const float wx1 = fx - x0f, wx0 = 1.f - wx1;
      const float wy1 = fy - y0f, wy0 = 1.f - wy1;
      const int x0 = (int)x0f, y0 = (int)y0f;
#pragma unroll
      for (int cy = 0; cy < 2; ++cy) {
        const float yyf = y0f + (float)cy;
        const float vy = (yyf >= 0.f && yyf <= 63.f) ? 1.f : 0.f;
        const int yc = min(max(y0 + cy, 0), 63);
        const float wyv = (cy ? wy1 : wy0) * vy;
#pragma unroll
        for (int cx = 0; cx < 2; ++cx) {
          const float xxf = x0f + (float)cx;
          const float vx = (xxf >= 0.f && xxf <= 63.f) ? 1.f : 0.f;
          const int xc = min(max(x0 + cx, 0), 63);
          const float wv = scale * wyv * (cx ? wx1 : wx0) * vx;
          const int ri = yc * WF_ + xc;
          const ushort8_t f8 =
              *(const ushort8_t*)&fb[(size_t)ri * 256 + l * 8];
#pragma unroll
          for (int j = 0; j < 8; ++j) smc[c][j] += wv * b2f(f8[j]);
        }
      }
    };
    if (same) {
      samplePoint(pcx[c] + offv[0], pcy[c] + offv[1], 1.f);
    } else {
#pragma unroll
      for (int p = 0; p < 4; ++p)
        samplePoint(pcx[c] + offv[2 * p], pcy[c] + offv[2 * p + 1], 0.25f);
    }
  }

  // 7 interleaved 5-stage butterflies (halves independent: offsets <= 16)
  float vals[7];
  vals[0] = dpg0;
#pragma unroll
  for (int c = 0; c < 6; ++c) {
    float d = 0.f;
#pragma unroll
    for (int j = 0; j < 8; ++j) d += tf[j] * smc[c][j];
    vals[1 + c] = d;
  }
#pragma unroll
  for (int o = 16; o > 0; o >>= 1) {
#pragma unroll
    for (int i = 0; i < 7; ++i) vals[i] += __shfl_xor(vals[i], o, 64);
  }
  const float gam = vals[0] + bqbk[0];

  float sv[8];
#pragma unroll
  for (int j = 0; j < 8; ++j) sv[j] = 0.f;
  float wsum = 0.f;
  int vcnt = 0;
#pragma unroll
  for (int c = 0; c < 6; ++c) {
    if (!validc[c]) continue;
    const float w = (vals[1 + c] + gam) * (1.f / 16.f);
#pragma unroll
    for (int j = 0; j < 8; ++j) sv[j] += w * smc[c][j];
    wsum += w;
    ++vcnt;
  }
  const float inv = 1.f / fmaxf((float)vcnt, 1.f);
  ushort8_t o8;
#pragma unroll
  for (int j = 0; j < 8; ++j) o8[j] = f2b(sv[j] * inv);
  *(ushort8_t*)&SVb[(size_t)m * 256 + l * 8] = o8;
  if (l == 0) wscale[m] = wsum * inv;
}

// ---------------------------------------------------------------------------
extern "C" void kernel_launch(void* const* d_in, const int* in_sizes, int n_in,
                              void* d_out, int out_size, void* d_ws,
                              size_t ws_size, hipStream_t stream) {
  const float* queries = (const float*)d_in[0];
  const float* feats = (const float*)d_in[1];
  const float* pix = (const float*)d_in[2];
  const int* vmask = (const int*)d_in[3];
  const float* Wq = (const float*)d_in[4];
  const float* bq = (const float*)d_in[5];
  const float* Wk = (const float*)d_in[6];
  const float* bk = (const float*)d_in[7];
  const float* Wv = (const float*)d_in[8];
  const float* bv = (const float*)d_in[9];
  const float* Wo = (const float*)d_in[10];
  const float* bo = (const float*)d_in[11];
  const float* Woff = (const float*)d_in[12];
  const float* boff = (const float*)d_in[13];
  const float* ln_g = (const float*)d_in[14];
  const float* ln_b = (const float*)d_in[15];

  char* w = (char*)d_ws;
  ushort_t* At = (ushort_t*)w;   w += 256 * 256 * 2;
  ushort_t* W2t = (ushort_t*)w;  w += 256 * 256 * 2;
  float* vec1 = (float*)w;       w += 1024;
  float* vec2 = (float*)w;       w += 1024;
  float* beta = (float*)w;       w += 1024;
  float* bqbk = (float*)w;       w += 256;
  float* WG05 = (float*)w;       w += 256;
  float* WBB05 = (float*)w;      w += 256;
  float* LNA = (float*)w;        w += (size_t)BN_ * 8 * 4;
  float* RSMU = (float*)w;       w += (size_t)BN_ * 4;
  float* WSC = (float*)w;        w += (size_t)BN_ * 4;
  ushort_t* QNb = (ushort_t*)w;  w += (size_t)BN_ * 256 * 2;  // SVb overlays
  ushort_t* SVb = QNb;
  ushort_t* featb = (ushort_t*)w;
  const size_t featElems = (size_t)B_ * C_ * HF_ * WF_ * 256;  // 12,582,912

  ushort_t* Tb = (ushort_t*)d_out;  // bf16 T lives in d_out until final GEMM
  float* out = (float*)d_out;

  k_rest<<<37 + BN_ / 8, 256, 0, stream>>>(
      Wq, Wk, Wv, Wo, bq, bk, bv, At, W2t, vec1, vec2, beta, bqbk,
      queries, ln_g, ln_b, Woff, boff, QNb, LNA, RSMU, WG05, WBB05);
  const int gemmBlocks = BN_ / 64 * 4;  // 1024
  const int cvtBlocks = 2048;
  k_mid<<<cvtBlocks + gemmBlocks, 256, 0, stream>>>(
      QNb, At, Tb, vec1, feats, featb, (int)(featElems / 4), cvtBlocks);
  k_sample<<<BN_ / 16, 512, 0, stream>>>(
      featb, pix, vmask, Tb, QNb, vec2, bqbk, LNA, RSMU, WG05, WBB05,
      SVb, WSC);
  k_gemm1<<<BN_ / 64 * 4, 256, 0, stream>>>(SVb, W2t, out, queries, WSC,
                                            beta, bo);
}

// Round 15
// 73.005 us; speedup vs baseline: 1.1418x; 1.1418x over previous
//
#include <hip/hip_runtime.h>
#include <hip/hip_bf16.h>
#include <math.h>

#define B_   2
#define N_   8192
#define D_   256
#define C_   6
#define HF_  64
#define WF_  64
#define P_   4
#define BN_  (B_ * N_)   // 16384

typedef __attribute__((ext_vector_type(8))) short short8v;   // 8 bf16 (4 VGPRs)
typedef __attribute__((ext_vector_type(4))) float floatx4;

typedef unsigned short ushort_t;
typedef __attribute__((ext_vector_type(4))) unsigned short ushort4_t;
typedef __attribute__((ext_vector_type(8))) unsigned short ushort8_t;

__device__ __forceinline__ float wred64(float v) {
#pragma unroll
  for (int o = 32; o > 0; o >>= 1) v += __shfl_xor(v, o, 64);
  return v;
}

__device__ __forceinline__ ushort_t f2b(float x) {
  union { float f; unsigned u; } c;
  c.f = x;
  unsigned r = c.u + 0x7FFFu + ((c.u >> 16) & 1u);
  return (ushort_t)(r >> 16);
}

__device__ __forceinline__ float b2f(ushort_t u) {
  union { unsigned u; float f; } c;
  c.u = ((unsigned)u) << 16;
  return c.f;
}

// ---------------------------------------------------------------------------
// K_rest:
//  blocks [0,32)   : weight products via MFMA, 64x64 tiles
//  blocks [32,36)  : vec1/vec2/beta, 64 outputs each, 4-way wave-parallel
//  block 36        : wg05/wbb05 (offset constants) + bqbk
//  blocks [37,+2048): LayerNorm, 2 rows per wave (32-lane halves, 8 ch/lane)
//    -> QNb (bf16) + LNA (0.05*rs*A_p) + RSMU
// ---------------------------------------------------------------------------
__global__ __launch_bounds__(256) void k_rest(
    const float* __restrict__ Wq, const float* __restrict__ Wk,
    const float* __restrict__ Wv, const float* __restrict__ Wo,
    const float* __restrict__ bq, const float* __restrict__ bk,
    const float* __restrict__ bv,
    ushort_t* __restrict__ At, ushort_t* __restrict__ W2t,
    float* __restrict__ vec1, float* __restrict__ vec2,
    float* __restrict__ beta, float* __restrict__ bqbk,
    const float* __restrict__ Q, const float* __restrict__ ln_g,
    const float* __restrict__ ln_b, const float* __restrict__ Woff,
    const float* __restrict__ boff, ushort_t* __restrict__ QNb,
    float* __restrict__ LNA, float* __restrict__ RSMU,
    float* __restrict__ WG05, float* __restrict__ WBB05) {
  __shared__ ushort_t Ak[64 * 68];   // 8.7 KB (reused as float scratch by vec)
  __shared__ ushort_t Bk[64 * 68];   // 8.7 KB
  const int blk = blockIdx.x;
  const int t = threadIdx.x;

  if (blk < 32) {
    const int prod = blk >> 4;
    const int tb = blk & 15;
    const int rb = (tb >> 2) * 64;   // output row base (j or d)
    const int cb = (tb & 3) * 64;    // output col base (i or e)
    const int wid = t >> 6, lane = t & 63;
    const int wm = wid >> 1, wn = wid & 1;
    const int lr = lane & 15, lh = lane >> 4;
    floatx4 acc[2][2];
#pragma unroll
    for (int i = 0; i < 2; ++i)
#pragma unroll
      for (int j = 0; j < 2; ++j) acc[i][j] = (floatx4){0.f, 0.f, 0.f, 0.f};

    for (int m0 = 0; m0 < 256; m0 += 64) {
      if (prod == 0) {
#pragma unroll
        for (int seg = 0; seg < 4; ++seg) {
          const int mm = (t >> 4) + seg * 16;  // 0..63
          const int cc = (t & 15) * 4;         // 0..60
          const float4 va = *(const float4*)&Wk[(m0 + mm) * 256 + rb + cc];
          Ak[(cc + 0) * 68 + mm] = f2b(va.x);
          Ak[(cc + 1) * 68 + mm] = f2b(va.y);
          Ak[(cc + 2) * 68 + mm] = f2b(va.z);
          Ak[(cc + 3) * 68 + mm] = f2b(va.w);
          const float4 vb = *(const float4*)&Wq[(m0 + mm) * 256 + cb + cc];
          Bk[(cc + 0) * 68 + mm] = f2b(vb.x);
          Bk[(cc + 1) * 68 + mm] = f2b(vb.y);
          Bk[(cc + 2) * 68 + mm] = f2b(vb.z);
          Bk[(cc + 3) * 68 + mm] = f2b(vb.w);
        }
      } else {
#pragma unroll
        for (int seg = 0; seg < 4; ++seg) {
          const int row = (t >> 4) + seg * 16;  // 0..63
          const int c4 = (t & 15) * 4;          // 0..60
          const float4 va = *(const float4*)&Wo[(rb + row) * 256 + m0 + c4];
          Ak[row * 68 + c4 + 0] = f2b(va.x);
          Ak[row * 68 + c4 + 1] = f2b(va.y);
          Ak[row * 68 + c4 + 2] = f2b(va.z);
          Ak[row * 68 + c4 + 3] = f2b(va.w);
          const float4 vb = *(const float4*)&Wv[(m0 + row) * 256 + cb + c4];
          Bk[(c4 + 0) * 68 + row] = f2b(vb.x);
          Bk[(c4 + 1) * 68 + row] = f2b(vb.y);
          Bk[(c4 + 2) * 68 + row] = f2b(vb.z);
          Bk[(c4 + 3) * 68 + row] = f2b(vb.w);
        }
      }
      __syncthreads();
#pragma unroll
      for (int kk = 0; kk < 64; kk += 32) {
        short8v a[2], b[2];
#pragma unroll
        for (int mi = 0; mi < 2; ++mi)
          a[mi] = *(const short8v*)&Ak[(wm * 32 + mi * 16 + lr) * 68 + kk + lh * 8];
#pragma unroll
        for (int ni = 0; ni < 2; ++ni)
          b[ni] = *(const short8v*)&Bk[(wn * 32 + ni * 16 + lr) * 68 + kk + lh * 8];
#pragma unroll
        for (int mi = 0; mi < 2; ++mi)
#pragma unroll
          for (int ni = 0; ni < 2; ++ni)
            acc[mi][ni] = __builtin_amdgcn_mfma_f32_16x16x32_bf16(
                a[mi], b[ni], acc[mi][ni], 0, 0, 0);
      }
      __syncthreads();
    }
    ushort_t* dst = prod ? W2t : At;
#pragma unroll
    for (int mi = 0; mi < 2; ++mi)
#pragma unroll
      for (int ni = 0; ni < 2; ++ni)
#pragma unroll
        for (int r = 0; r < 4; ++r)
          dst[(size_t)(rb + wm * 32 + mi * 16 + lh * 4 + r) * 256 +
              cb + wn * 32 + ni * 16 + lr] = f2b(acc[mi][ni][r]);
    return;
  }

  if (blk < 36) {
    // vec1/vec2/beta: 64 outputs per block, 4 waves split the m-range.
    const int vb = blk - 32;
    const int i = t & 63, seg = t >> 6;
    const int ii = vb * 64 + i;
    float a2 = 0.f, a1 = 0.f, ab = 0.f;
#pragma unroll 4
    for (int mq = 0; mq < 64; ++mq) {
      const int m = seg * 64 + mq;
      a2 += Wq[m * 256 + ii] * bk[m];
      a1 += Wk[m * 256 + ii] * bq[m];
      ab += Wo[ii * 256 + m] * bv[m];
    }
    float* sc = (float*)Ak;  // 768 floats scratch
    sc[seg * 64 + i] = a2;
    sc[256 + seg * 64 + i] = a1;
    sc[512 + seg * 64 + i] = ab;
    __syncthreads();
    if (t < 64) {
      vec2[vb * 64 + t] = sc[t] + sc[64 + t] + sc[128 + t] + sc[192 + t];
      vec1[vb * 64 + t] =
          sc[256 + t] + sc[320 + t] + sc[384 + t] + sc[448 + t];
      beta[vb * 64 + t] =
          sc[512 + t] + sc[576 + t] + sc[640 + t] + sc[704 + t];
    }
    return;
  }

  if (blk == 36) {
    // offset constants + bqbk
    if (t < 8) {
      float wg = 0.f;
#pragma unroll 8
      for (int d = 0; d < 256; ++d) wg += Woff[t * 256 + d] * ln_g[d];
      WG05[t] = 0.05f * wg;
    } else if (t < 16) {
      const int p = t - 8;
      float wb = 0.f;
#pragma unroll 8
      for (int d = 0; d < 256; ++d) wb += Woff[p * 256 + d] * ln_b[d];
      WBB05[p] = 0.05f * (wb + boff[p]);
    } else if (t >= 64 && t < 128) {
      const int l = t - 64;
      float s = 0.f;
#pragma unroll
      for (int q = 0; q < 4; ++q) {
        const int m = l + q * 64;
        s += bq[m] * bk[m];
      }
      s = wred64(s);
      if (l == 0) *bqbk = s;
    }
    return;
  }

  // ---- LayerNorm: 2 rows per wave (32-lane halves, 8 channels/lane).
  // Single 10-value 5-stage butterfly (s, sq, A[8]).
  const int lb = blk - 37;
  const int wave = t >> 6, lane = t & 63;
  const int half = lane >> 5, l = lane & 31;
  const int m = lb * 8 + wave * 2 + half;
  const int base = m * 256 + l * 8;
  const float4 x0 = *(const float4*)&Q[base];
  const float4 x1 = *(const float4*)&Q[base + 4];
  const float4 g0 = *(const float4*)&ln_g[l * 8];
  const float4 g1 = *(const float4*)&ln_g[l * 8 + 4];
  const float4 b0 = *(const float4*)&ln_b[l * 8];
  const float4 b1 = *(const float4*)&ln_b[l * 8 + 4];
  float xv[8] = {x0.x, x0.y, x0.z, x0.w, x1.x, x1.y, x1.z, x1.w};
  float gv[8] = {g0.x, g0.y, g0.z, g0.w, g1.x, g1.y, g1.z, g1.w};
  float bv8[8] = {b0.x, b0.y, b0.z, b0.w, b1.x, b1.y, b1.z, b1.w};
  float red[10];
  red[0] = 0.f;
  red[1] = 0.f;
#pragma unroll
  for (int j = 0; j < 8; ++j) {
    red[0] += xv[j];
    red[1] += xv[j] * xv[j];
  }
#pragma unroll
  for (int p = 0; p < 8; ++p) {
    const float4 w0 = *(const float4*)&Woff[p * 256 + l * 8];
    const float4 w1 = *(const float4*)&Woff[p * 256 + l * 8 + 4];
    red[2 + p] = w0.x * gv[0] * xv[0] + w0.y * gv[1] * xv[1] +
                 w0.z * gv[2] * xv[2] + w0.w * gv[3] * xv[3] +
                 w1.x * gv[4] * xv[4] + w1.y * gv[5] * xv[5] +
                 w1.z * gv[6] * xv[6] + w1.w * gv[7] * xv[7];
  }
#pragma unroll
  for (int o = 16; o > 0; o >>= 1) {
#pragma unroll
    for (int i = 0; i < 10; ++i) red[i] += __shfl_xor(red[i], o, 64);
  }
  const float mu = red[0] * (1.0f / 256.0f);
  const float var = red[1] * (1.0f / 256.0f) - mu * mu;
  const float rs = rsqrtf(var + 1e-5f);
  ushort8_t qo;
#pragma unroll
  for (int j = 0; j < 8; ++j)
    qo[j] = f2b((xv[j] - mu) * rs * gv[j] + bv8[j]);
  *(ushort8_t*)&QNb[base] = qo;
  if (l == 0) {
    const float s05 = 0.05f * rs;
    float4 o0, o1;
    o0.x = s05 * red[2]; o0.y = s05 * red[3];
    o0.z = s05 * red[4]; o0.w = s05 * red[5];
    o1.x = s05 * red[6]; o1.y = s05 * red[7];
    o1.z = s05 * red[8]; o1.w = s05 * red[9];
    *(float4*)&LNA[m * 8] = o0;
    *(float4*)&LNA[m * 8 + 4] = o1;
    RSMU[m] = rs * mu;
  }
}

// ---------------------------------------------------------------------------
// K_mid: merged GEMM0 + feature cvt (gemm blocks first, cvt backfills).
// ---------------------------------------------------------------------------
__global__ __launch_bounds__(256) void k_mid(
    const ushort_t* __restrict__ Xb, const ushort_t* __restrict__ Wt,
    ushort_t* __restrict__ Yout, const float* __restrict__ vec1,
    const float* __restrict__ f, ushort_t* __restrict__ fb, int totalVec4,
    int gemmBlocks) {
  __shared__ ushort_t As[64 * 68];
  __shared__ ushort_t Bs[64 * 68];
  __shared__ float tr[4][16 * 17];
  const int t = threadIdx.x;

  if (blockIdx.x >= gemmBlocks) {
    const int cvtGrid = gridDim.x - gemmBlocks;
    const int stride = cvtGrid * 256;
    for (int i = (blockIdx.x - gemmBlocks) * 256 + t; i < totalVec4;
         i += stride) {
      const float4 v = *(const float4*)&f[(size_t)i * 4];
      ushort4_t o;
      o.x = f2b(v.x); o.y = f2b(v.y); o.z = f2b(v.z); o.w = f2b(v.w);
      *(ushort4_t*)&fb[(size_t)i * 4] = o;
    }
    return;
  }

  const int nb = blockIdx.x & 3, mb = blockIdx.x >> 2;
  const int m0 = mb * 64, n0 = nb * 64;
  const int wid = t >> 6, lane = t & 63;
  const int wm = wid >> 1, wn = wid & 1;
  const int lr = lane & 15, lh = lane >> 4;

  floatx4 acc[2][2];
#pragma unroll
  for (int i = 0; i < 2; ++i)
#pragma unroll
    for (int j = 0; j < 2; ++j) acc[i][j] = (floatx4){0.f, 0.f, 0.f, 0.f};

  for (int k0 = 0; k0 < 256; k0 += 64) {
#pragma unroll
    for (int q = 0; q < 2; ++q) {
      const int s = t * 2 + q;
      const int row = s >> 3;
      const int off = (s & 7) * 8;
      *(float4*)&As[row * 68 + off] =
          *(const float4*)(Xb + (size_t)(m0 + row) * 256 + k0 + off);
      *(float4*)&Bs[row * 68 + off] =
          *(const float4*)(Wt + (size_t)(n0 + row) * 256 + k0 + off);
    }
    __syncthreads();
#pragma unroll
    for (int kk = 0; kk < 64; kk += 32) {
      short8v a[2], b[2];
#pragma unroll
      for (int mi = 0; mi < 2; ++mi)
        a[mi] = *(const short8v*)&As[(wm * 32 + mi * 16 + lr) * 68 + kk + lh * 8];
#pragma unroll
      for (int ni = 0; ni < 2; ++ni)
        b[ni] = *(const short8v*)&Bs[(wn * 32 + ni * 16 + lr) * 68 + kk + lh * 8];
#pragma unroll
      for (int mi = 0; mi < 2; ++mi)
#pragma unroll
        for (int ni = 0; ni < 2; ++ni)
          acc[mi][ni] = __builtin_amdgcn_mfma_f32_16x16x32_bf16(
              a[mi], b[ni], acc[mi][ni], 0, 0, 0);
    }
    __syncthreads();
  }

  float* tb = tr[wid];
#pragma unroll
  for (int mi = 0; mi < 2; ++mi) {
#pragma unroll
    for (int ni = 0; ni < 2; ++ni) {
#pragma unroll
      for (int r = 0; r < 4; ++r)
        tb[(lh * 4 + r) * 17 + lr] = acc[mi][ni][r];
      const float4 v = *(const float4*)&tb[lr * 17 + lh * 4];
      const int row = m0 + wm * 32 + mi * 16 + lr;
      const int col = n0 + wn * 32 + ni * 16 + lh * 4;
      const float4 vc = *(const float4*)&vec1[col];
      ushort4_t o;
      o.x = f2b(v.x + vc.x);
      o.y = f2b(v.y + vc.y);
      o.z = f2b(v.z + vc.z);
      o.w = f2b(v.w + vc.w);
      *(ushort4_t*)(Yout + (size_t)row * 256 + col) = o;
    }
  }
}

// ---------------------------------------------------------------------------
// Final GEMM: out = SVb @ W2t^T + resid + wsc*beta + bo (f32 out).
// ---------------------------------------------------------------------------
__global__ __launch_bounds__(256) void k_gemm1(
    const ushort_t* __restrict__ Xb, const ushort_t* __restrict__ Wt,
    float* __restrict__ Yout, const float* __restrict__ resid,
    const float* __restrict__ wsc, const float* __restrict__ beta,
    const float* __restrict__ bo) {
  __shared__ ushort_t As[64 * 68];
  __shared__ ushort_t Bs[64 * 68];
  __shared__ float tr[4][16 * 17];
  const int t = threadIdx.x;
  const int nb = blockIdx.x & 3, mb = blockIdx.x >> 2;
  const int m0 = mb * 64, n0 = nb * 64;
  const int wid = t >> 6, lane = t & 63;
  const int wm = wid >> 1, wn = wid & 1;
  const int lr = lane & 15, lh = lane >> 4;

  floatx4 acc[2][2];
#pragma unroll
  for (int i = 0; i < 2; ++i)
#pragma unroll
    for (int j = 0; j < 2; ++j) acc[i][j] = (floatx4){0.f, 0.f, 0.f, 0.f};

  for (int k0 = 0; k0 < 256; k0 += 64) {
#pragma unroll
    for (int q = 0; q < 2; ++q) {
      const int s = t * 2 + q;
      const int row = s >> 3;
      const int off = (s & 7) * 8;
      *(float4*)&As[row * 68 + off] =
          *(const float4*)(Xb + (size_t)(m0 + row) * 256 + k0 + off);
      *(float4*)&Bs[row * 68 + off] =
          *(const float4*)(Wt + (size_t)(n0 + row) * 256 + k0 + off);
    }
    __syncthreads();
#pragma unroll
    for (int kk = 0; kk < 64; kk += 32) {
      short8v a[2], b[2];
#pragma unroll
      for (int mi = 0; mi < 2; ++mi)
        a[mi] = *(const short8v*)&As[(wm * 32 + mi * 16 + lr) * 68 + kk + lh * 8];
#pragma unroll
      for (int ni = 0; ni < 2; ++ni)
        b[ni] = *(const short8v*)&Bs[(wn * 32 + ni * 16 + lr) * 68 + kk + lh * 8];
#pragma unroll
      for (int mi = 0; mi < 2; ++mi)
#pragma unroll
        for (int ni = 0; ni < 2; ++ni)
          acc[mi][ni] = __builtin_amdgcn_mfma_f32_16x16x32_bf16(
              a[mi], b[ni], acc[mi][ni], 0, 0, 0);
    }
    __syncthreads();
  }

  float* tb = tr[wid];
#pragma unroll
  for (int mi = 0; mi < 2; ++mi) {
#pragma unroll
    for (int ni = 0; ni < 2; ++ni) {
#pragma unroll
      for (int r = 0; r < 4; ++r)
        tb[(lh * 4 + r) * 17 + lr] = acc[mi][ni][r];
      const float4 v = *(const float4*)&tb[lr * 17 + lh * 4];
      const int row = m0 + wm * 32 + mi * 16 + lr;
      const int col = n0 + wn * 32 + ni * 16 + lh * 4;
      const float4 rv = *(const float4*)&resid[(size_t)row * 256 + col];
      const float4 bt = *(const float4*)&beta[col];
      const float4 bv4 = *(const float4*)&bo[col];
      const float wscale = wsc[row];
      float4 o;
      o.x = v.x + rv.x + wscale * bt.x + bv4.x;
      o.y = v.y + rv.y + wscale * bt.y + bv4.y;
      o.z = v.z + rv.z + wscale * bt.z + bv4.z;
      o.w = v.w + rv.w + wscale * bt.w + bv4.w;
      *(float4*)&Yout[(size_t)row * 256 + col] = o;
    }
  }
}

// ---------------------------------------------------------------------------
// Fused sampling + scores + aggregation. 2 queries per wave (32-lane halves,
// 8 channels/lane, 16B gathers). 5-stage interleaved butterflies.
// ---------------------------------------------------------------------------
template <typename FT>
__global__ __launch_bounds__(256) void k_sample(
    const FT* __restrict__ feats, const float* __restrict__ pix,
    const int* __restrict__ vmask, const ushort_t* __restrict__ Tb,
    const ushort_t* __restrict__ QNb, const float* __restrict__ vec2,
    const float* __restrict__ bqbk, const float* __restrict__ LNA,
    const float* __restrict__ RSMU, const float* __restrict__ WG05,
    const float* __restrict__ WBB05, ushort_t* __restrict__ SVb,
    float* __restrict__ wscale) {
  const int wave = threadIdx.x >> 6, lane = threadIdx.x & 63;
  const int half = lane >> 5, l = lane & 31;
  const int m = blockIdx.x * 8 + wave * 2 + half;
  const int b = m >> 13, n = m & 8191;

  const ushort8_t tu = *(const ushort8_t*)&Tb[(size_t)m * 256 + l * 8];
  float tf[8];
#pragma unroll
  for (int j = 0; j < 8; ++j) tf[j] = b2f(tu[j]);

  float dpg0;
  {
    const ushort8_t qu = *(const ushort8_t*)&QNb[(size_t)m * 256 + l * 8];
    const float4 v20 = *(const float4*)&vec2[l * 8];
    const float4 v21 = *(const float4*)&vec2[l * 8 + 4];
    dpg0 = v20.x * b2f(qu[0]) + v20.y * b2f(qu[1]) + v20.z * b2f(qu[2]) +
           v20.w * b2f(qu[3]) + v21.x * b2f(qu[4]) + v21.y * b2f(qu[5]) +
           v21.z * b2f(qu[6]) + v21.w * b2f(qu[7]);
  }

  float offv[8];
  {
    const float4 a0 = *(const float4*)&LNA[m * 8];
    const float4 a1 = *(const float4*)&LNA[m * 8 + 4];
    const float rsmu = RSMU[m];
    const float4 wg0 = *(const float4*)&WG05[0];
    const float4 wg1 = *(const float4*)&WG05[4];
    const float4 wb0 = *(const float4*)&WBB05[0];
    const float4 wb1 = *(const float4*)&WBB05[4];
    offv[0] = a0.x - rsmu * wg0.x + wb0.x;
    offv[1] = a0.y - rsmu * wg0.y + wb0.y;
    offv[2] = a0.z - rsmu * wg0.z + wb0.z;
    offv[3] = a0.w - rsmu * wg0.w + wb0.w;
    offv[4] = a1.x - rsmu * wg1.x + wb1.x;
    offv[5] = a1.y - rsmu * wg1.y + wb1.y;
    offv[6] = a1.z - rsmu * wg1.z + wb1.z;
    offv[7] = a1.w - rsmu * wg1.w + wb1.w;
  }
  const bool same = (offv[0] == offv[2]) && (offv[0] == offv[4]) &&
                    (offv[0] == offv[6]) && (offv[1] == offv[3]) &&
                    (offv[1] == offv[5]) && (offv[1] == offv[7]);

  int validc[6];
  float pcx[6], pcy[6];
#pragma unroll
  for (int c = 0; c < 6; ++c) {
    const int idx = (b * 6 + c) * 8192 + n;
    validc[c] = vmask[idx];
    pcx[c] = pix[(size_t)idx * 2 + 0];
    pcy[c] = pix[(size_t)idx * 2 + 1];
  }

  float smc[6][8];
#pragma unroll
  for (int c = 0; c < 6; ++c)
#pragma unroll
    for (int j = 0; j < 8; ++j) smc[c][j] = 0.f;

#pragma unroll
  for (int c = 0; c < 6; ++c) {
    if (!validc[c]) continue;
    const FT* fb = feats + (size_t)(b * 6 + c) * (HF_ * WF_ * 256);
    auto samplePoint = [&](float gx, float gy, float scale) {
      const float fx = (gx + 1.f) * 31.5f;
      const float fy = (gy + 1.f) * 31.5f;
      const float x0f = floorf(fx), y0f = floorf(fy);
      const float wx1 = fx - x0f, wx0 = 1.f - wx1;
      const float wy1 = fy - y0f, wy0 = 1.f - wy1;
      const int x0 = (int)x0f, y0 = (int)y0f;
#pragma unroll
      for (int cy = 0; cy < 2; ++cy) {
        const float yyf = y0f + (float)cy;
        const float vy = (yyf >= 0.f && yyf <= 63.f) ? 1.f : 0.f;
        const int yc = min(max(y0 + cy, 0), 63);
        const float wyv = (cy ? wy1 : wy0) * vy;
#pragma unroll
        for (int cx = 0; cx < 2; ++cx) {
          const float xxf = x0f + (float)cx;
          const float vx = (xxf >= 0.f && xxf <= 63.f) ? 1.f : 0.f;
          const int xc = min(max(x0 + cx, 0), 63);
          const float wv = scale * wyv * (cx ? wx1 : wx0) * vx;
          const int ri = yc * WF_ + xc;
          if constexpr (sizeof(FT) == 2) {
            const ushort8_t f8 =
                *(const ushort8_t*)&fb[(size_t)ri * 256 + l * 8];
#pragma unroll
            for (int j = 0; j < 8; ++j) smc[c][j] += wv * b2f(f8[j]);
          } else {
            const float4 f0 = *(const float4*)&fb[(size_t)ri * 256 + l * 8];
            const float4 f1 =
                *(const float4*)&fb[(size_t)ri * 256 + l * 8 + 4];
            smc[c][0] += wv * f0.x; smc[c][1] += wv * f0.y;
            smc[c][2] += wv * f0.z; smc[c][3] += wv * f0.w;
            smc[c][4] += wv * f1.x; smc[c][5] += wv * f1.y;
            smc[c][6] += wv * f1.z; smc[c][7] += wv * f1.w;
          }
        }
      }
    };
    if (same) {
      samplePoint(pcx[c] + offv[0], pcy[c] + offv[1], 1.f);
    } else {
#pragma unroll
      for (int p = 0; p < 4; ++p)
        samplePoint(pcx[c] + offv[2 * p], pcy[c] + offv[2 * p + 1], 0.25f);
    }
  }

  // 7 interleaved 5-stage butterflies (halves independent: offsets <= 16)
  float vals[7];
  vals[0] = dpg0;
#pragma unroll
  for (int c = 0; c < 6; ++c) {
    float d = 0.f;
#pragma unroll
    for (int j = 0; j < 8; ++j) d += tf[j] * smc[c][j];
    vals[1 + c] = d;
  }
#pragma unroll
  for (int o = 16; o > 0; o >>= 1) {
#pragma unroll
    for (int i = 0; i < 7; ++i) vals[i] += __shfl_xor(vals[i], o, 64);
  }
  const float gam = vals[0] + bqbk[0];

  float sv[8];
#pragma unroll
  for (int j = 0; j < 8; ++j) sv[j] = 0.f;
  float wsum = 0.f;
  int vcnt = 0;
#pragma unroll
  for (int c = 0; c < 6; ++c) {
    if (!validc[c]) continue;
    const float w = (vals[1 + c] + gam) * (1.f / 16.f);
#pragma unroll
    for (int j = 0; j < 8; ++j) sv[j] += w * smc[c][j];
    wsum += w;
    ++vcnt;
  }
  const float inv = 1.f / fmaxf((float)vcnt, 1.f);
  ushort8_t o8;
#pragma unroll
  for (int j = 0; j < 8; ++j) o8[j] = f2b(sv[j] * inv);
  *(ushort8_t*)&SVb[(size_t)m * 256 + l * 8] = o8;
  if (l == 0) wscale[m] = wsum * inv;
}

// ---------------------------------------------------------------------------
extern "C" void kernel_launch(void* const* d_in, const int* in_sizes, int n_in,
                              void* d_out, int out_size, void* d_ws,
                              size_t ws_size, hipStream_t stream) {
  const float* queries = (const float*)d_in[0];
  const float* feats = (const float*)d_in[1];
  const float* pix = (const float*)d_in[2];
  const int* vmask = (const int*)d_in[3];
  const float* Wq = (const float*)d_in[4];
  const float* bq = (const float*)d_in[5];
  const float* Wk = (const float*)d_in[6];
  const float* bk = (const float*)d_in[7];
  const float* Wv = (const float*)d_in[8];
  const float* bv = (const float*)d_in[9];
  const float* Wo = (const float*)d_in[10];
  const float* bo = (const float*)d_in[11];
  const float* Woff = (const float*)d_in[12];
  const float* boff = (const float*)d_in[13];
  const float* ln_g = (const float*)d_in[14];
  const float* ln_b = (const float*)d_in[15];

  char* w = (char*)d_ws;
  ushort_t* At = (ushort_t*)w;   w += 256 * 256 * 2;
  ushort_t* W2t = (ushort_t*)w;  w += 256 * 256 * 2;
  float* vec1 = (float*)w;       w += 1024;
  float* vec2 = (float*)w;       w += 1024;
  float* beta = (float*)w;       w += 1024;
  float* bqbk = (float*)w;       w += 256;
  float* WG05 = (float*)w;       w += 256;
  float* WBB05 = (float*)w;      w += 256;
  float* LNA = (float*)w;        w += (size_t)BN_ * 8 * 4;
  float* RSMU = (float*)w;       w += (size_t)BN_ * 4;
  float* WSC = (float*)w;        w += (size_t)BN_ * 4;
  ushort_t* QNb = (ushort_t*)w;  w += (size_t)BN_ * 256 * 2;  // SVb overlays
  ushort_t* SVb = QNb;
  ushort_t* featb = (ushort_t*)w;
  const size_t featElems = (size_t)B_ * C_ * HF_ * WF_ * 256;  // 12,582,912
  const size_t need = (size_t)(w - (char*)d_ws) + featElems * 2;
  const bool useBf16Feat = (ws_size >= need);

  ushort_t* Tb = (ushort_t*)d_out;  // bf16 T lives in d_out until final GEMM
  float* out = (float*)d_out;

  k_rest<<<37 + BN_ / 8, 256, 0, stream>>>(
      Wq, Wk, Wv, Wo, bq, bk, bv, At, W2t, vec1, vec2, beta, bqbk,
      queries, ln_g, ln_b, Woff, boff, QNb, LNA, RSMU, WG05, WBB05);
  const int gemmBlocks = BN_ / 64 * 4;  // 1024
  if (useBf16Feat) {
    k_mid<<<gemmBlocks + 2048, 256, 0, stream>>>(
        QNb, At, Tb, vec1, feats, featb, (int)(featElems / 4), gemmBlocks);
    k_sample<ushort_t><<<BN_ / 8, 256, 0, stream>>>(
        featb, pix, vmask, Tb, QNb, vec2, bqbk, LNA, RSMU, WG05, WBB05,
        SVb, WSC);
  } else {
    k_mid<<<gemmBlocks, 256, 0, stream>>>(
        QNb, At, Tb, vec1, nullptr, nullptr, 0, gemmBlocks);
    k_sample<float><<<BN_ / 8, 256, 0, stream>>>(
        feats, pix, vmask, Tb, QNb, vec2, bqbk, LNA, RSMU, WG05, WBB05,
        SVb, WSC);
  }
  k_gemm1<<<BN_ / 64 * 4, 256, 0, stream>>>(SVb, W2t, out, queries, WSC,
                                            beta, bo);
}